// Round 6
// baseline (195.148 us; speedup 1.0000x reference)
//
#include <hip/hip_runtime.h>

// ---------------------------------------------------------------------------
// MABClean: setnorm -> {Q,K,V} proj -> 8-head attention -> O proj + residual
//           -> setnorm -> relu -> Wres proj + residual.
// B=4, Nx=Ny=2048, d_model=256, heads=8, head_dim=32. All f32 in/out.
// Attention: swapped QK^T (lane-local rows), raw v_exp_f32, cvt_pkrtz packing,
// sched_barrier-pinned V + K-prefetch pipeline, XCD-aware block swizzle.
// ---------------------------------------------------------------------------

typedef _Float16 f16;
typedef _Float16 f16x4 __attribute__((ext_vector_type(4)));
typedef _Float16 f16x8 __attribute__((ext_vector_type(8)));
typedef float f32x4 __attribute__((ext_vector_type(4)));
typedef unsigned int u32;
typedef unsigned int u32x2 __attribute__((ext_vector_type(2)));

#define DEV static __device__ __forceinline__

DEV void load_lds16(const void* g, void* s) {
  __builtin_amdgcn_global_load_lds(
      (const __attribute__((address_space(1))) void*)g,
      (__attribute__((address_space(3))) void*)s, 16, 0, 0);
}

DEV float fexp2(float x) {
  float r;
  asm("v_exp_f32 %0, %1" : "=v"(r) : "v"(x));
  return r;
}

DEV u32 pkh(float a, float b) {
  auto h = __builtin_amdgcn_cvt_pkrtz(a, b);  // __fp16 ext_vector(2)
  return __builtin_bit_cast(u32, h);
}

// ---------------- set-norm statistics (two-stage, deterministic) -----------
__global__ __launch_bounds__(256) void stats_partial(const float* __restrict__ p0,
                                                     const float* __restrict__ p1,
                                                     float2* __restrict__ partial) {
  const int s = blockIdx.y;
  const float* p = (s >= 4 ? p1 + (size_t)(s - 4) * 524288 : p0 + (size_t)s * 524288)
                   + (size_t)blockIdx.x * 8192;
  float sum = 0.f, ss = 0.f;
#pragma unroll
  for (int j = 0; j < 8; ++j) {
    f32x4 v = *reinterpret_cast<const f32x4*>(p + (size_t)(j * 256 + threadIdx.x) * 4);
#pragma unroll
    for (int e = 0; e < 4; ++e) { sum += v[e]; ss += v[e] * v[e]; }
  }
#pragma unroll
  for (int m = 1; m < 64; m <<= 1) { sum += __shfl_xor(sum, m); ss += __shfl_xor(ss, m); }
  __shared__ float2 red[4];
  if ((threadIdx.x & 63) == 0) red[threadIdx.x >> 6] = make_float2(sum, ss);
  __syncthreads();
  if (threadIdx.x == 0) {
    float a = 0.f, b = 0.f;
    for (int i = 0; i < 4; ++i) { a += red[i].x; b += red[i].y; }
    partial[s * 64 + blockIdx.x] = make_float2(a, b);
  }
}

__global__ void stats_final(const float2* __restrict__ partial, float2* __restrict__ stats) {
  const int s = blockIdx.x;
  float2 v = partial[s * 64 + threadIdx.x];
  float sum = v.x, ss = v.y;
#pragma unroll
  for (int m = 1; m < 64; m <<= 1) { sum += __shfl_xor(sum, m); ss += __shfl_xor(ss, m); }
  if (threadIdx.x == 0) {
    const float invN = 1.f / 524288.f;
    float mean = sum * invN;
    float var = fmaxf(ss * invN - mean * mean, 0.f);
    stats[s] = make_float2(mean, rsqrtf(var + 1e-5f));
  }
}

// ---------------- f32 -> f16 prep (optional fused setnorm / relu) ----------
template <bool NORM, bool RELU>
__global__ __launch_bounds__(256) void prep_cast(const float* __restrict__ in, f16* __restrict__ out,
                                                 const float2* __restrict__ stats, int sbase,
                                                 const float* __restrict__ w, const float* __restrict__ b) {
  const size_t i8 = (size_t)blockIdx.x * 256 + threadIdx.x;
  const size_t idx = i8 * 8;
  float mean = 0.f, istd = 1.f;
  if (NORM) { float2 st = stats[sbase + (int)(idx >> 19)]; mean = st.x; istd = st.y; }
  const int f = (int)(idx & 255);
  f32x4 v0 = *reinterpret_cast<const f32x4*>(in + idx);
  f32x4 v1 = *reinterpret_cast<const f32x4*>(in + idx + 4);
  f32x4 w0, w1, b0, b1;
  if (NORM) {
    w0 = *reinterpret_cast<const f32x4*>(w + f);
    w1 = *reinterpret_cast<const f32x4*>(w + f + 4);
    b0 = *reinterpret_cast<const f32x4*>(b + f);
    b1 = *reinterpret_cast<const f32x4*>(b + f + 4);
  }
  f16x8 o;
#pragma unroll
  for (int j = 0; j < 4; ++j) {
    float x0 = v0[j], x1 = v1[j];
    if (NORM) { x0 = (x0 - mean) * istd * w0[j] + b0[j]; x1 = (x1 - mean) * istd * w1[j] + b1[j]; }
    if (RELU) { x0 = fmaxf(x0, 0.f); x1 = fmaxf(x1, 0.f); }
    o[j] = (f16)x0;
    o[j + 4] = (f16)x1;
  }
  *reinterpret_cast<f16x8*>(out + idx) = o;
}

// weights: 5 x [256x256] f32 -> concat f16. grid 160 x 256.
__global__ __launch_bounds__(256) void cast_w(const float* __restrict__ w0, const float* __restrict__ w1,
                                              const float* __restrict__ w2, const float* __restrict__ w3,
                                              const float* __restrict__ w4, f16* __restrict__ out) {
  const int i8 = blockIdx.x * 256 + threadIdx.x;  // 0..40959
  const int mat = i8 >> 13;
  const size_t off = (size_t)(i8 & 8191) * 8;
  const float* src = mat == 0 ? w0 : mat == 1 ? w1 : mat == 2 ? w2 : mat == 3 ? w3 : w4;
  f32x4 v0 = *reinterpret_cast<const f32x4*>(src + off);
  f32x4 v1 = *reinterpret_cast<const f32x4*>(src + off + 4);
  f16x8 o;
#pragma unroll
  for (int j = 0; j < 4; ++j) { o[j] = (f16)v0[j]; o[j + 4] = (f16)v1[j]; }
  *reinterpret_cast<f16x8*>(out + (size_t)mat * 65536 + off) = o;
}

// ---------------- GEMM: C[8192][256] = A[8192][256] . W[256][256]^T --------
enum { GM_F16 = 0, GM_VT = 1, GM_F32R = 2 };

template <int MODE>
__global__ __launch_bounds__(256) void gemm_nt(const f16* __restrict__ A, const f16* __restrict__ W,
                                               const float* __restrict__ bias,
                                               const float* __restrict__ resid,
                                               void* __restrict__ outp, float scale) {
  __shared__ __align__(16) f16 lds[4096];  // A: [kg4][row64][8], B: same, 4KB each
  const int t = threadIdx.x;
  const int w = t >> 6, lane = t & 63;
  const int g = lane >> 4, lq = lane & 15;
  const int m0 = blockIdx.x * 64, n0 = blockIdx.y * 64;
  const int wr = (w >> 1) * 32, wc = (w & 1) * 32;

  f32x4 acc[2][2] = {};
  f16* ldsA = lds;
  f16* ldsB = lds + 2048;
  const f16* gA = A + (size_t)(m0 + lane) * 256 + w * 8;
  const f16* gB = W + (size_t)(n0 + lane) * 256 + w * 8;
  f16* dA = ldsA + t * 8;
  f16* dB = ldsB + t * 8;

  for (int kt = 0; kt < 8; ++kt) {
    __syncthreads();
    load_lds16(gA + kt * 32, dA);
    load_lds16(gB + kt * 32, dB);
    __syncthreads();
    f16x8 af[2], bfr[2];
#pragma unroll
    for (int i = 0; i < 2; ++i)
      af[i] = *reinterpret_cast<const f16x8*>(ldsA + g * 512 + (wr + i * 16 + lq) * 8);
#pragma unroll
    for (int j = 0; j < 2; ++j)
      bfr[j] = *reinterpret_cast<const f16x8*>(ldsB + g * 512 + (wc + j * 16 + lq) * 8);
#pragma unroll
    for (int i = 0; i < 2; ++i)
#pragma unroll
      for (int j = 0; j < 2; ++j)
        acc[i][j] = __builtin_amdgcn_mfma_f32_16x16x32_f16(af[i], bfr[j], acc[i][j], 0, 0, 0);
  }

#pragma unroll
  for (int i = 0; i < 2; ++i)
#pragma unroll
    for (int j = 0; j < 2; ++j) {
      const int row0 = m0 + wr + i * 16 + g * 4;
      const int col = n0 + wc + j * 16 + lq;
      const float bv = bias[col];
#pragma unroll
      for (int r = 0; r < 4; ++r) {
        const int rr = row0 + r;
        float v = (acc[i][j][r] + bv) * scale;
        if constexpr (MODE == GM_F16) {
          ((f16*)outp)[(size_t)rr * 256 + col] = (f16)v;
        } else if constexpr (MODE == GM_VT) {
          ((f16*)outp)[((size_t)(rr >> 11) * 256 + col) * 2048 + (rr & 2047)] = (f16)v;
        } else {
          const size_t o = (size_t)rr * 256 + col;
          ((float*)outp)[o] = v + resid[o];
        }
      }
    }
}

// ---------------- flash attention --------------------------------------------
// grid 1024 (1D, XCD-swizzled), 256 thr = 4 waves, wave = 16 q-rows.
// Q pre-scaled by log2(e)/16 (exp2 domain). K: [B*2048][256]. Vt: [B][256][2048].
// Swapped QK^T: s = mfma(kf, qf) -> lane holds q-row (lane&15), k = c*16+g*4+r.
// __launch_bounds__(256,3): allow ~170 VGPR so the V + K-prefetch registers
// stay allocated; sched_barrier(0) pins the loads above the compute phase.
__global__ __launch_bounds__(256, 3) void attn_kernel(const f16* __restrict__ Q,
                                                      const f16* __restrict__ K,
                                                      const f16* __restrict__ Vt,
                                                      f16* __restrict__ O) {
  __shared__ __align__(16) f16 plds[4][1024];  // per-wave P tile [16 q][64 k], XOR-swizzled
  const int t = threadIdx.x;
  const int w = t >> 6, lane = t & 63;
  const int g = lane >> 4, lq = lane & 15;
  // XCD-aware decode: hardware round-robins blockIdx across 8 XCDs; remap so
  // each XCD gets 128 consecutive linear ids = 4 (h,b) K/V slices (1MB < L2).
  const int wg = blockIdx.x;                       // 0..1023
  const int linear = (wg & 7) * 128 + (wg >> 3);   // bijective (1024 % 8 == 0)
  const int qt = linear & 31;
  const int hb = linear >> 5;
  const int h = hb & 7, b = hb >> 3;
  const int q0 = qt * 64 + w * 16;
  const float THR = 8.0f;

  const f16* Kb = K + (size_t)b * 2048 * 256 + h * 32;
  const f16* Vb = Vt + ((size_t)b * 256 + h * 32) * 2048;
  f16* myp = plds[w];

  const f16x8 qf =
      *reinterpret_cast<const f16x8*>(Q + (size_t)(b * 2048 + q0 + lq) * 256 + h * 32 + g * 8);

  // hoisted LDS addresses (XOR swizzle on elem bits 3..5 with q&7)
  const int xq = (lq & 7) << 3;
  f16* wp0 = myp + ((lq * 64 + g * 4 + 0) ^ xq);
  f16* wp1 = myp + ((lq * 64 + g * 4 + 16) ^ xq);
  f16* wp2 = myp + ((lq * 64 + g * 4 + 32) ^ xq);
  f16* wp3 = myp + ((lq * 64 + g * 4 + 48) ^ xq);
  const f16* rp0 = myp + ((lq * 64 + 0 + g * 8) ^ xq);
  const f16* rp1 = myp + ((lq * 64 + 32 + g * 8) ^ xq);

  // running global pointers (pointer-bump, no per-tile 64-bit recompute)
  const int KSTEP = 64 * 256;  // elems per k-tile of K
  const f16* kp0 = Kb + (size_t)(0 * 16 + lq) * 256 + g * 8;
  const f16* kp1 = Kb + (size_t)(1 * 16 + lq) * 256 + g * 8;
  const f16* kp2 = Kb + (size_t)(2 * 16 + lq) * 256 + g * 8;
  const f16* kp3 = Kb + (size_t)(3 * 16 + lq) * 256 + g * 8;
  const f16* vp0 = Vb + (size_t)lq * 2048 + g * 8;
  const f16* vp1 = Vb + (size_t)(16 + lq) * 2048 + g * 8;

  // prologue: load K tile 0
  f16x8 ka0 = *reinterpret_cast<const f16x8*>(kp0);
  f16x8 ka1 = *reinterpret_cast<const f16x8*>(kp1);
  f16x8 ka2 = *reinterpret_cast<const f16x8*>(kp2);
  f16x8 ka3 = *reinterpret_cast<const f16x8*>(kp3);
  f16x8 kb0, kb1, kb2, kb3;

  f32x4 o0 = {0.f, 0.f, 0.f, 0.f}, o1 = {0.f, 0.f, 0.f, 0.f};
  float m_ = -1e30f;  // running row max (exp2 domain)
  float l_ = 0.f;     // per-lane partial row sum

  auto body = [&](f16x8& c0, f16x8& c1, f16x8& c2, f16x8& c3,
                  f16x8& n0, f16x8& n1, f16x8& n2, f16x8& n3) {
    // issue V(t) + K(t+1) loads; the fence below forbids the compiler from
    // sinking them to their uses (that register-saving sink is what exposed
    // full memory latency in rounds 2-5: VGPR_Count was only 60).
    f16x8 v00 = *reinterpret_cast<const f16x8*>(vp0);
    f16x8 v01 = *reinterpret_cast<const f16x8*>(vp0 + 32);
    f16x8 v10 = *reinterpret_cast<const f16x8*>(vp1);
    f16x8 v11 = *reinterpret_cast<const f16x8*>(vp1 + 32);
    vp0 += 64; vp1 += 64;
    kp0 += KSTEP; kp1 += KSTEP; kp2 += KSTEP; kp3 += KSTEP;
    // last iteration reads one tile past K into the weights buffer: mapped, unused
    n0 = *reinterpret_cast<const f16x8*>(kp0);
    n1 = *reinterpret_cast<const f16x8*>(kp1);
    n2 = *reinterpret_cast<const f16x8*>(kp2);
    n3 = *reinterpret_cast<const f16x8*>(kp3);
    __builtin_amdgcn_sched_barrier(0);

    // QK^T (swapped operands): lane holds q-row = lq, k-slots c*16 + g*4 + r
    const f32x4 z = {0.f, 0.f, 0.f, 0.f};
    __builtin_amdgcn_s_setprio(1);
    f32x4 s0 = __builtin_amdgcn_mfma_f32_16x16x32_f16(c0, qf, z, 0, 0, 0);
    f32x4 s1 = __builtin_amdgcn_mfma_f32_16x16x32_f16(c1, qf, z, 0, 0, 0);
    f32x4 s2 = __builtin_amdgcn_mfma_f32_16x16x32_f16(c2, qf, z, 0, 0, 0);
    f32x4 s3 = __builtin_amdgcn_mfma_f32_16x16x32_f16(c3, qf, z, 0, 0, 0);
    __builtin_amdgcn_s_setprio(0);

    // row max: max3 trees (8 ops) + 2 cross-g shuffles
    float t0 = fmaxf(fmaxf(s0[0], s0[1]), s0[2]);
    float t1 = fmaxf(fmaxf(s0[3], s1[0]), s1[1]);
    float t2 = fmaxf(fmaxf(s1[2], s1[3]), s2[0]);
    float t3 = fmaxf(fmaxf(s2[1], s2[2]), s2[3]);
    float t4 = fmaxf(fmaxf(s3[0], s3[1]), s3[2]);
    float x = fmaxf(fmaxf(fmaxf(t0, t1), fmaxf(t2, t3)), fmaxf(t4, s3[3]));
    x = fmaxf(x, __shfl_xor(x, 16));
    x = fmaxf(x, __shfl_xor(x, 32));

    if (__any(x > m_ + THR)) {  // defer-max rescale (rare after first tile)
      const float mnew = fmaxf(m_, x);
      const float sc = fexp2(m_ - mnew);
      m_ = mnew;
      l_ *= sc;
#pragma unroll
      for (int r = 0; r < 4; ++r) {
        const float scq = __shfl(sc, g * 4 + r);
        o0[r] *= scq;
        o1[r] *= scq;
      }
    }

    // p = exp2(s - m): raw v_exp_f32 (flush-to-zero below -126 is fine here)
    float e00 = fexp2(s0[0] - m_), e01 = fexp2(s0[1] - m_), e02 = fexp2(s0[2] - m_), e03 = fexp2(s0[3] - m_);
    float e10 = fexp2(s1[0] - m_), e11 = fexp2(s1[1] - m_), e12 = fexp2(s1[2] - m_), e13 = fexp2(s1[3] - m_);
    float e20 = fexp2(s2[0] - m_), e21 = fexp2(s2[1] - m_), e22 = fexp2(s2[2] - m_), e23 = fexp2(s2[3] - m_);
    float e30 = fexp2(s3[0] - m_), e31 = fexp2(s3[1] - m_), e32 = fexp2(s3[2] - m_), e33 = fexp2(s3[3] - m_);
    const float la = (e00 + e01) + (e02 + e03);
    const float lb = (e10 + e11) + (e12 + e13);
    const float lc = (e20 + e21) + (e22 + e23);
    const float ld = (e30 + e31) + (e32 + e33);
    l_ += (la + lb) + (lc + ld);

    // pack P to f16 (cvt_pkrtz) and write 4 x b64 to LDS
    u32x2 w0q = {pkh(e00, e01), pkh(e02, e03)};
    u32x2 w1q = {pkh(e10, e11), pkh(e12, e13)};
    u32x2 w2q = {pkh(e20, e21), pkh(e22, e23)};
    u32x2 w3q = {pkh(e30, e31), pkh(e32, e33)};
    *reinterpret_cast<u32x2*>(wp0) = w0q;
    *reinterpret_cast<u32x2*>(wp1) = w1q;
    *reinterpret_cast<u32x2*>(wp2) = w2q;
    *reinterpret_cast<u32x2*>(wp3) = w3q;

    // PV (V loads in flight since tile top; counted vmcnt wait here)
    f16x8 pa0 = *reinterpret_cast<const f16x8*>(rp0);
    f16x8 pa1 = *reinterpret_cast<const f16x8*>(rp1);
    __builtin_amdgcn_s_setprio(1);
    o0 = __builtin_amdgcn_mfma_f32_16x16x32_f16(pa0, v00, o0, 0, 0, 0);
    o1 = __builtin_amdgcn_mfma_f32_16x16x32_f16(pa0, v10, o1, 0, 0, 0);
    o0 = __builtin_amdgcn_mfma_f32_16x16x32_f16(pa1, v01, o0, 0, 0, 0);
    o1 = __builtin_amdgcn_mfma_f32_16x16x32_f16(pa1, v11, o1, 0, 0, 0);
    __builtin_amdgcn_s_setprio(0);
  };

  for (int kt = 0; kt < 32; kt += 2) {
    body(ka0, ka1, ka2, ka3, kb0, kb1, kb2, kb3);
    body(kb0, kb1, kb2, kb3, ka0, ka1, ka2, ka3);
  }

  // combine partial sums across the 4 g-lanes of each q-row
  float lf = l_ + __shfl_xor(l_, 16);
  lf += __shfl_xor(lf, 32);
#pragma unroll
  for (int r = 0; r < 4; ++r) {
    const float lr = __shfl(lf, g * 4 + r);  // l for q = g*4+r
    const float inv = 1.f / lr;
    const size_t row = (size_t)b * 2048 + q0 + g * 4 + r;
    O[row * 256 + h * 32 + lq] = (f16)(o0[r] * inv);
    O[row * 256 + h * 32 + 16 + lq] = (f16)(o1[r] * inv);
  }
}

// ---------------------------------------------------------------------------
extern "C" void kernel_launch(void* const* d_in, const int* in_sizes, int n_in,
                              void* d_out, int out_size, void* d_ws, size_t ws_size,
                              hipStream_t stream) {
  (void)in_sizes; (void)n_in; (void)out_size; (void)ws_size;
  const float* X    = (const float*)d_in[0];
  const float* Y    = (const float*)d_in[1];
  const float* Wq   = (const float*)d_in[2];
  const float* bq   = (const float*)d_in[3];
  const float* Wk   = (const float*)d_in[4];
  const float* bk   = (const float*)d_in[5];
  const float* Wv   = (const float*)d_in[6];
  const float* bv   = (const float*)d_in[7];
  const float* Wo   = (const float*)d_in[8];
  const float* bo   = (const float*)d_in[9];
  const float* Wres = (const float*)d_in[10];
  const float* bres = (const float*)d_in[11];
  const float* nq_w = (const float*)d_in[12];
  const float* nq_b = (const float*)d_in[13];
  const float* nk_w = (const float*)d_in[14];
  const float* nk_b = (const float*)d_in[15];
  const float* n0_w = (const float*)d_in[16];
  const float* n0_b = (const float*)d_in[17];
  float* out = (float*)d_out;

  // workspace layout (compact, ~21.1 MB total)
  char* ws = (char*)d_ws;
  const size_t MB = 1u << 20;
  f16* bufA = (f16*)(ws + 0 * MB);    // Xn   -> later Vt
  f16* bufB = (f16*)(ws + 4 * MB);    // Yn   -> later attn out
  f16* bufC = (f16*)(ws + 8 * MB);    // Ycast-> later relu(setnorm(H1))
  f16* bufQ = (f16*)(ws + 12 * MB);
  f16* bufK = (f16*)(ws + 16 * MB);
  f16* bufW = (f16*)(ws + 20 * MB);   // 5 x 65536 f16 = 640 KiB
  float2* partial = (float2*)(ws + 21 * MB);          // 8*64 float2 = 4 KiB
  float2* stats   = (float2*)(ws + 21 * MB + 4096);   // 8 float2

  // 1. set-norm stats for X (slices 0-3) and Y (slices 4-7)
  stats_partial<<<dim3(64, 8), 256, 0, stream>>>(X, Y, partial);
  stats_final<<<8, 64, 0, stream>>>(partial, stats);

  // 2. f16 preps (2097152 elems / 8 per thread = 1024 blocks)
  prep_cast<true, false><<<1024, 256, 0, stream>>>(X, bufA, stats, 0, nq_w, nq_b);
  prep_cast<true, false><<<1024, 256, 0, stream>>>(Y, bufB, stats, 4, nk_w, nk_b);
  prep_cast<false, false><<<1024, 256, 0, stream>>>(Y, bufC, stats, 0, nq_w, nq_b);
  cast_w<<<160, 256, 0, stream>>>(Wq, Wk, Wv, Wo, Wres, bufW);

  // 3. projections. Q pre-scaled by log2(e)/sqrt(256) (exp2 domain);
  //    V stored transposed per batch.
  const float qscale = 1.4426950408889634f / 16.f;
  gemm_nt<GM_F16><<<dim3(128, 4), 256, 0, stream>>>(bufA, bufW + 0 * 65536, bq, nullptr, bufQ, qscale);
  gemm_nt<GM_F16><<<dim3(128, 4), 256, 0, stream>>>(bufB, bufW + 1 * 65536, bk, nullptr, bufK, 1.f);
  gemm_nt<GM_VT ><<<dim3(128, 4), 256, 0, stream>>>(bufC, bufW + 2 * 65536, bv, nullptr, bufA, 1.f);

  // 4. attention (out -> bufB), 1D grid with XCD-aware decode inside
  attn_kernel<<<1024, 256, 0, stream>>>(bufQ, bufK, bufA, bufB);

  // 5. O projection + X residual -> H1 (in d_out, f32)
  gemm_nt<GM_F32R><<<dim3(128, 4), 256, 0, stream>>>(bufB, bufW + 3 * 65536, bo, X, out, 1.f);

  // 6. stats over H1, relu(setnorm(H1)) -> bufC
  stats_partial<<<dim3(64, 4), 256, 0, stream>>>(out, out, partial);
  stats_final<<<4, 64, 0, stream>>>(partial, stats);
  prep_cast<true, true><<<1024, 256, 0, stream>>>(out, bufC, stats, 0, n0_w, n0_b);

  // 7. final: out = H1 + relu(setnorm(H1)) @ Wres^T + bres (in-place per element)
  gemm_nt<GM_F32R><<<dim3(128, 4), 256, 0, stream>>>(bufC, bufW + 4 * 65536, bres, out, out, 1.f);
}

// Round 7
// 120.311 us; speedup vs baseline: 1.6220x; 1.6220x over previous
//
#include <hip/hip_runtime.h>

// ---------------------------------------------------------------------------
// MABClean: setnorm -> {Q,K,V} proj -> 8-head attention -> O proj + residual
//           -> setnorm -> relu -> Wres proj + residual.
// B=4, Nx=Ny=2048, d_model=256, heads=8, head_dim=32. All f32 in/out.
// Attention: block-cooperative double-buffered LDS staging of K/V tiles
// (global_load_lds, swizzled), swapped QK^T, raw v_exp_f32, defer-max.
// ---------------------------------------------------------------------------

typedef _Float16 f16;
typedef _Float16 f16x4 __attribute__((ext_vector_type(4)));
typedef _Float16 f16x8 __attribute__((ext_vector_type(8)));
typedef float f32x4 __attribute__((ext_vector_type(4)));
typedef unsigned int u32;
typedef unsigned int u32x2 __attribute__((ext_vector_type(2)));

#define DEV static __device__ __forceinline__

DEV void load_lds16(const void* g, void* s) {
  __builtin_amdgcn_global_load_lds(
      (const __attribute__((address_space(1))) void*)g,
      (__attribute__((address_space(3))) void*)s, 16, 0, 0);
}

DEV float fexp2(float x) {
  float r;
  asm("v_exp_f32 %0, %1" : "=v"(r) : "v"(x));
  return r;
}

DEV u32 pkh(float a, float b) {
  auto h = __builtin_amdgcn_cvt_pkrtz(a, b);  // __fp16 ext_vector(2)
  return __builtin_bit_cast(u32, h);
}

// ---------------- set-norm statistics (two-stage, deterministic) -----------
__global__ __launch_bounds__(256) void stats_partial(const float* __restrict__ p0,
                                                     const float* __restrict__ p1,
                                                     float2* __restrict__ partial) {
  const int s = blockIdx.y;
  const float* p = (s >= 4 ? p1 + (size_t)(s - 4) * 524288 : p0 + (size_t)s * 524288)
                   + (size_t)blockIdx.x * 8192;
  float sum = 0.f, ss = 0.f;
#pragma unroll
  for (int j = 0; j < 8; ++j) {
    f32x4 v = *reinterpret_cast<const f32x4*>(p + (size_t)(j * 256 + threadIdx.x) * 4);
#pragma unroll
    for (int e = 0; e < 4; ++e) { sum += v[e]; ss += v[e] * v[e]; }
  }
#pragma unroll
  for (int m = 1; m < 64; m <<= 1) { sum += __shfl_xor(sum, m); ss += __shfl_xor(ss, m); }
  __shared__ float2 red[4];
  if ((threadIdx.x & 63) == 0) red[threadIdx.x >> 6] = make_float2(sum, ss);
  __syncthreads();
  if (threadIdx.x == 0) {
    float a = 0.f, b = 0.f;
    for (int i = 0; i < 4; ++i) { a += red[i].x; b += red[i].y; }
    partial[s * 64 + blockIdx.x] = make_float2(a, b);
  }
}

__global__ void stats_final(const float2* __restrict__ partial, float2* __restrict__ stats) {
  const int s = blockIdx.x;
  float2 v = partial[s * 64 + threadIdx.x];
  float sum = v.x, ss = v.y;
#pragma unroll
  for (int m = 1; m < 64; m <<= 1) { sum += __shfl_xor(sum, m); ss += __shfl_xor(ss, m); }
  if (threadIdx.x == 0) {
    const float invN = 1.f / 524288.f;
    float mean = sum * invN;
    float var = fmaxf(ss * invN - mean * mean, 0.f);
    stats[s] = make_float2(mean, rsqrtf(var + 1e-5f));
  }
}

// ---------------- f32 -> f16 prep (optional fused setnorm / relu) ----------
template <bool NORM, bool RELU>
__global__ __launch_bounds__(256) void prep_cast(const float* __restrict__ in, f16* __restrict__ out,
                                                 const float2* __restrict__ stats, int sbase,
                                                 const float* __restrict__ w, const float* __restrict__ b) {
  const size_t i8 = (size_t)blockIdx.x * 256 + threadIdx.x;
  const size_t idx = i8 * 8;
  float mean = 0.f, istd = 1.f;
  if (NORM) { float2 st = stats[sbase + (int)(idx >> 19)]; mean = st.x; istd = st.y; }
  const int f = (int)(idx & 255);
  f32x4 v0 = *reinterpret_cast<const f32x4*>(in + idx);
  f32x4 v1 = *reinterpret_cast<const f32x4*>(in + idx + 4);
  f32x4 w0, w1, b0, b1;
  if (NORM) {
    w0 = *reinterpret_cast<const f32x4*>(w + f);
    w1 = *reinterpret_cast<const f32x4*>(w + f + 4);
    b0 = *reinterpret_cast<const f32x4*>(b + f);
    b1 = *reinterpret_cast<const f32x4*>(b + f + 4);
  }
  f16x8 o;
#pragma unroll
  for (int j = 0; j < 4; ++j) {
    float x0 = v0[j], x1 = v1[j];
    if (NORM) { x0 = (x0 - mean) * istd * w0[j] + b0[j]; x1 = (x1 - mean) * istd * w1[j] + b1[j]; }
    if (RELU) { x0 = fmaxf(x0, 0.f); x1 = fmaxf(x1, 0.f); }
    o[j] = (f16)x0;
    o[j + 4] = (f16)x1;
  }
  *reinterpret_cast<f16x8*>(out + idx) = o;
}

// weights: 5 x [256x256] f32 -> concat f16. grid 160 x 256.
__global__ __launch_bounds__(256) void cast_w(const float* __restrict__ w0, const float* __restrict__ w1,
                                              const float* __restrict__ w2, const float* __restrict__ w3,
                                              const float* __restrict__ w4, f16* __restrict__ out) {
  const int i8 = blockIdx.x * 256 + threadIdx.x;  // 0..40959
  const int mat = i8 >> 13;
  const size_t off = (size_t)(i8 & 8191) * 8;
  const float* src = mat == 0 ? w0 : mat == 1 ? w1 : mat == 2 ? w2 : mat == 3 ? w3 : w4;
  f32x4 v0 = *reinterpret_cast<const f32x4*>(src + off);
  f32x4 v1 = *reinterpret_cast<const f32x4*>(src + off + 4);
  f16x8 o;
#pragma unroll
  for (int j = 0; j < 4; ++j) { o[j] = (f16)v0[j]; o[j + 4] = (f16)v1[j]; }
  *reinterpret_cast<f16x8*>(out + (size_t)mat * 65536 + off) = o;
}

// ---------------- GEMM: C[8192][256] = A[8192][256] . W[256][256]^T --------
enum { GM_F16 = 0, GM_VT = 1, GM_F32R = 2 };

template <int MODE>
__global__ __launch_bounds__(256) void gemm_nt(const f16* __restrict__ A, const f16* __restrict__ W,
                                               const float* __restrict__ bias,
                                               const float* __restrict__ resid,
                                               void* __restrict__ outp, float scale) {
  __shared__ __align__(16) f16 lds[4096];  // A: [kg4][row64][8], B: same, 4KB each
  const int t = threadIdx.x;
  const int w = t >> 6, lane = t & 63;
  const int g = lane >> 4, lq = lane & 15;
  const int m0 = blockIdx.x * 64, n0 = blockIdx.y * 64;
  const int wr = (w >> 1) * 32, wc = (w & 1) * 32;

  f32x4 acc[2][2] = {};
  f16* ldsA = lds;
  f16* ldsB = lds + 2048;
  const f16* gA = A + (size_t)(m0 + lane) * 256 + w * 8;
  const f16* gB = W + (size_t)(n0 + lane) * 256 + w * 8;
  f16* dA = ldsA + t * 8;
  f16* dB = ldsB + t * 8;

  for (int kt = 0; kt < 8; ++kt) {
    __syncthreads();
    load_lds16(gA + kt * 32, dA);
    load_lds16(gB + kt * 32, dB);
    __syncthreads();
    f16x8 af[2], bfr[2];
#pragma unroll
    for (int i = 0; i < 2; ++i)
      af[i] = *reinterpret_cast<const f16x8*>(ldsA + g * 512 + (wr + i * 16 + lq) * 8);
#pragma unroll
    for (int j = 0; j < 2; ++j)
      bfr[j] = *reinterpret_cast<const f16x8*>(ldsB + g * 512 + (wc + j * 16 + lq) * 8);
#pragma unroll
    for (int i = 0; i < 2; ++i)
#pragma unroll
      for (int j = 0; j < 2; ++j)
        acc[i][j] = __builtin_amdgcn_mfma_f32_16x16x32_f16(af[i], bfr[j], acc[i][j], 0, 0, 0);
  }

#pragma unroll
  for (int i = 0; i < 2; ++i)
#pragma unroll
    for (int j = 0; j < 2; ++j) {
      const int row0 = m0 + wr + i * 16 + g * 4;
      const int col = n0 + wc + j * 16 + lq;
      const float bv = bias[col];
#pragma unroll
      for (int r = 0; r < 4; ++r) {
        const int rr = row0 + r;
        float v = (acc[i][j][r] + bv) * scale;
        if constexpr (MODE == GM_F16) {
          ((f16*)outp)[(size_t)rr * 256 + col] = (f16)v;
        } else if constexpr (MODE == GM_VT) {
          ((f16*)outp)[((size_t)(rr >> 11) * 256 + col) * 2048 + (rr & 2047)] = (f16)v;
        } else {
          const size_t o = (size_t)rr * 256 + col;
          ((float*)outp)[o] = v + resid[o];
        }
      }
    }
}

// ---------------- flash attention --------------------------------------------
// grid 1024 (1D, XCD-swizzled), 256 thr = 4 waves, wave = 16 q-rows.
// Q pre-scaled by log2(e)/16 (exp2 domain). K: [B*2048][256]. Vt: [B][256][2048].
// Block-cooperative staging: K tile [64][32] + V tile [32][64] f16 in LDS,
// double-buffered via global_load_lds; XOR col-swizzles (applied to the global
// source per rule "both-sides-or-neither") make the frag ds_read_b128 reads
// conflict-free. Stage(t+1) issued before compute(t); __syncthreads' vmcnt(0)
// drain is the phase boundary (T3 minimum 2-phase).
__global__ __launch_bounds__(256) void attn_kernel(const f16* __restrict__ Q,
                                                   const f16* __restrict__ K,
                                                   const f16* __restrict__ Vt,
                                                   f16* __restrict__ O) {
  __shared__ __align__(16) f16 kbuf[2][2048];  // [64 k-rows][32 d], col-swizzled
  __shared__ __align__(16) f16 vbuf[2][2048];  // [32 d-rows][64 k], col-swizzled
  __shared__ __align__(16) f16 plds[4][1024];  // per-wave P tile [16 q][64 k]
  const int t = threadIdx.x;
  const int w = t >> 6, lane = t & 63;
  const int g = lane >> 4, lq = lane & 15;
  // XCD-aware decode (r6: dropped FETCH 35->6 MB; keep)
  const int wg = blockIdx.x;                       // 0..1023
  const int linear = (wg & 7) * 128 + (wg >> 3);   // bijective (1024 % 8 == 0)
  const int qt = linear & 31;
  const int hb = linear >> 5;
  const int h = hb & 7, b = hb >> 3;
  const int q0 = qt * 64 + w * 16;
  const float THR = 8.0f;

  const f16* Kb = K + (size_t)b * 2048 * 256 + h * 32;
  const f16* Vb = Vt + ((size_t)b * 256 + h * 32) * 2048;
  f16* myp = plds[w];

  const f16x8 qf =
      *reinterpret_cast<const f16x8*>(Q + (size_t)(b * 2048 + q0 + lq) * 256 + h * 32 + g * 8);

  // ---- staging pointers (thread t loads 16B -> LDS slot t*16B, linear) ----
  // K: lds slot (row=t>>2, colgrp t&3); content = global colgrp swizzled by
  // SWK(row,c)=c^(row&3)^((row>>2)&3)  [involution]
  const f16* gK = Kb + (size_t)(t >> 2) * 256 +
                  (((t & 3) ^ ((t >> 2) & 3) ^ ((t >> 4) & 3)) << 3);
  // V: lds slot (row=t>>3, colgrp t&7); SWV(row,c)=c^(row&7)
  const f16* gV = Vb + (size_t)(t >> 3) * 2048 + ((((t & 7) ^ ((t >> 3) & 7))) << 3);
  f16* dKa = &kbuf[0][0] + t * 8;
  f16* dKb = &kbuf[1][0] + t * 8;
  f16* dVa = &vbuf[0][0] + t * 8;
  f16* dVb = &vbuf[1][0] + t * 8;
  const int KSTEP = 64 * 256;

  // ---- frag read offsets (swizzled; conflict-free by construction) ----
  const int swk = ((g ^ (lq & 3) ^ ((lq >> 2) & 3)) << 3);  // K colgrp
  const int kro = lq * 32 + swk;                            // + c*512 per c
  const int svA = ((g ^ (lq & 7)) << 3);                    // V colgrp ch=0
  const int svB = (((4 + g) ^ (lq & 7)) << 3);              // V colgrp ch=1
  const int vr0 = lq * 64, vr1 = (16 + lq) * 64;

  // P-tile pointers (unchanged from r3-r6, verified)
  const int xq = (lq & 7) << 3;
  f16* wp0 = myp + ((lq * 64 + g * 4 + 0) ^ xq);
  f16* wp1 = myp + ((lq * 64 + g * 4 + 16) ^ xq);
  f16* wp2 = myp + ((lq * 64 + g * 4 + 32) ^ xq);
  f16* wp3 = myp + ((lq * 64 + g * 4 + 48) ^ xq);
  const f16* rp0 = myp + ((lq * 64 + 0 + g * 8) ^ xq);
  const f16* rp1 = myp + ((lq * 64 + 32 + g * 8) ^ xq);

  f32x4 o0 = {0.f, 0.f, 0.f, 0.f}, o1 = {0.f, 0.f, 0.f, 0.f};
  float m_ = -1e30f;  // running row max (exp2 domain)
  float l_ = 0.f;     // per-lane partial row sum

  auto compute = [&](int buf) {  // buf is a literal at each call site
    const f16* kb = &kbuf[buf][0];
    const f16* vb = &vbuf[buf][0];
    f16x8 kf0 = *reinterpret_cast<const f16x8*>(kb + kro);
    f16x8 kf1 = *reinterpret_cast<const f16x8*>(kb + 512 + kro);
    f16x8 kf2 = *reinterpret_cast<const f16x8*>(kb + 1024 + kro);
    f16x8 kf3 = *reinterpret_cast<const f16x8*>(kb + 1536 + kro);

    const f32x4 z = {0.f, 0.f, 0.f, 0.f};
    __builtin_amdgcn_s_setprio(1);
    f32x4 s0 = __builtin_amdgcn_mfma_f32_16x16x32_f16(kf0, qf, z, 0, 0, 0);
    f32x4 s1 = __builtin_amdgcn_mfma_f32_16x16x32_f16(kf1, qf, z, 0, 0, 0);
    f32x4 s2 = __builtin_amdgcn_mfma_f32_16x16x32_f16(kf2, qf, z, 0, 0, 0);
    f32x4 s3 = __builtin_amdgcn_mfma_f32_16x16x32_f16(kf3, qf, z, 0, 0, 0);
    __builtin_amdgcn_s_setprio(0);

    // row max: max3 trees + 2 cross-g shuffles
    float t0 = fmaxf(fmaxf(s0[0], s0[1]), s0[2]);
    float t1 = fmaxf(fmaxf(s0[3], s1[0]), s1[1]);
    float t2 = fmaxf(fmaxf(s1[2], s1[3]), s2[0]);
    float t3 = fmaxf(fmaxf(s2[1], s2[2]), s2[3]);
    float t4 = fmaxf(fmaxf(s3[0], s3[1]), s3[2]);
    float x = fmaxf(fmaxf(fmaxf(t0, t1), fmaxf(t2, t3)), fmaxf(t4, s3[3]));
    x = fmaxf(x, __shfl_xor(x, 16));
    x = fmaxf(x, __shfl_xor(x, 32));

    if (__any(x > m_ + THR)) {  // defer-max rescale (rare after first tile)
      const float mnew = fmaxf(m_, x);
      const float sc = fexp2(m_ - mnew);
      m_ = mnew;
      l_ *= sc;
#pragma unroll
      for (int r = 0; r < 4; ++r) {
        const float scq = __shfl(sc, g * 4 + r);
        o0[r] *= scq;
        o1[r] *= scq;
      }
    }

    float e00 = fexp2(s0[0] - m_), e01 = fexp2(s0[1] - m_), e02 = fexp2(s0[2] - m_), e03 = fexp2(s0[3] - m_);
    float e10 = fexp2(s1[0] - m_), e11 = fexp2(s1[1] - m_), e12 = fexp2(s1[2] - m_), e13 = fexp2(s1[3] - m_);
    float e20 = fexp2(s2[0] - m_), e21 = fexp2(s2[1] - m_), e22 = fexp2(s2[2] - m_), e23 = fexp2(s2[3] - m_);
    float e30 = fexp2(s3[0] - m_), e31 = fexp2(s3[1] - m_), e32 = fexp2(s3[2] - m_), e33 = fexp2(s3[3] - m_);
    const float la = (e00 + e01) + (e02 + e03);
    const float lb = (e10 + e11) + (e12 + e13);
    const float lc = (e20 + e21) + (e22 + e23);
    const float ld = (e30 + e31) + (e32 + e33);
    l_ += (la + lb) + (lc + ld);

    u32x2 w0q = {pkh(e00, e01), pkh(e02, e03)};
    u32x2 w1q = {pkh(e10, e11), pkh(e12, e13)};
    u32x2 w2q = {pkh(e20, e21), pkh(e22, e23)};
    u32x2 w3q = {pkh(e30, e31), pkh(e32, e33)};
    *reinterpret_cast<u32x2*>(wp0) = w0q;
    *reinterpret_cast<u32x2*>(wp1) = w1q;
    *reinterpret_cast<u32x2*>(wp2) = w2q;
    *reinterpret_cast<u32x2*>(wp3) = w3q;

    f16x8 pa0 = *reinterpret_cast<const f16x8*>(rp0);
    f16x8 pa1 = *reinterpret_cast<const f16x8*>(rp1);
    f16x8 v00 = *reinterpret_cast<const f16x8*>(vb + vr0 + svA);
    f16x8 v01 = *reinterpret_cast<const f16x8*>(vb + vr0 + svB);
    f16x8 v10 = *reinterpret_cast<const f16x8*>(vb + vr1 + svA);
    f16x8 v11 = *reinterpret_cast<const f16x8*>(vb + vr1 + svB);
    __builtin_amdgcn_s_setprio(1);
    o0 = __builtin_amdgcn_mfma_f32_16x16x32_f16(pa0, v00, o0, 0, 0, 0);
    o1 = __builtin_amdgcn_mfma_f32_16x16x32_f16(pa0, v10, o1, 0, 0, 0);
    o0 = __builtin_amdgcn_mfma_f32_16x16x32_f16(pa1, v01, o0, 0, 0, 0);
    o1 = __builtin_amdgcn_mfma_f32_16x16x32_f16(pa1, v11, o1, 0, 0, 0);
    __builtin_amdgcn_s_setprio(0);
  };

  // prologue: stage tile 0 into buf 0
  load_lds16(gK, dKa);
  load_lds16(gV, dVa);
  gK += KSTEP; gV += 64;
  __syncthreads();

  for (int kt = 0; kt < 32; kt += 2) {
    // compute tile kt (buf0), stage tile kt+1 (buf1)
    load_lds16(gK, dKb);
    load_lds16(gV, dVb);
    gK += KSTEP; gV += 64;
    compute(0);
    __syncthreads();
    // compute tile kt+1 (buf1), stage tile kt+2 (buf0) unless done
    if (kt < 30) {
      load_lds16(gK, dKa);
      load_lds16(gV, dVa);
      gK += KSTEP; gV += 64;
    }
    compute(1);
    __syncthreads();
  }

  // combine partial sums across the 4 g-lanes of each q-row
  float lf = l_ + __shfl_xor(l_, 16);
  lf += __shfl_xor(lf, 32);
#pragma unroll
  for (int r = 0; r < 4; ++r) {
    const float lr = __shfl(lf, g * 4 + r);  // l for q = g*4+r
    const float inv = 1.f / lr;
    const size_t row = (size_t)b * 2048 + q0 + g * 4 + r;
    O[row * 256 + h * 32 + lq] = (f16)(o0[r] * inv);
    O[row * 256 + h * 32 + 16 + lq] = (f16)(o1[r] * inv);
  }
}

// ---------------------------------------------------------------------------
extern "C" void kernel_launch(void* const* d_in, const int* in_sizes, int n_in,
                              void* d_out, int out_size, void* d_ws, size_t ws_size,
                              hipStream_t stream) {
  (void)in_sizes; (void)n_in; (void)out_size; (void)ws_size;
  const float* X    = (const float*)d_in[0];
  const float* Y    = (const float*)d_in[1];
  const float* Wq   = (const float*)d_in[2];
  const float* bq   = (const float*)d_in[3];
  const float* Wk   = (const float*)d_in[4];
  const float* bk   = (const float*)d_in[5];
  const float* Wv   = (const float*)d_in[6];
  const float* bv   = (const float*)d_in[7];
  const float* Wo   = (const float*)d_in[8];
  const float* bo   = (const float*)d_in[9];
  const float* Wres = (const float*)d_in[10];
  const float* bres = (const float*)d_in[11];
  const float* nq_w = (const float*)d_in[12];
  const float* nq_b = (const float*)d_in[13];
  const float* nk_w = (const float*)d_in[14];
  const float* nk_b = (const float*)d_in[15];
  const float* n0_w = (const float*)d_in[16];
  const float* n0_b = (const float*)d_in[17];
  float* out = (float*)d_out;

  // workspace layout (compact, ~21.1 MB total)
  char* ws = (char*)d_ws;
  const size_t MB = 1u << 20;
  f16* bufA = (f16*)(ws + 0 * MB);    // Xn   -> later Vt
  f16* bufB = (f16*)(ws + 4 * MB);    // Yn   -> later attn out
  f16* bufC = (f16*)(ws + 8 * MB);    // Ycast-> later relu(setnorm(H1))
  f16* bufQ = (f16*)(ws + 12 * MB);
  f16* bufK = (f16*)(ws + 16 * MB);
  f16* bufW = (f16*)(ws + 20 * MB);   // 5 x 65536 f16 = 640 KiB
  float2* partial = (float2*)(ws + 21 * MB);          // 8*64 float2 = 4 KiB
  float2* stats   = (float2*)(ws + 21 * MB + 4096);   // 8 float2

  // 1. set-norm stats for X (slices 0-3) and Y (slices 4-7)
  stats_partial<<<dim3(64, 8), 256, 0, stream>>>(X, Y, partial);
  stats_final<<<8, 64, 0, stream>>>(partial, stats);

  // 2. f16 preps (2097152 elems / 8 per thread = 1024 blocks)
  prep_cast<true, false><<<1024, 256, 0, stream>>>(X, bufA, stats, 0, nq_w, nq_b);
  prep_cast<true, false><<<1024, 256, 0, stream>>>(Y, bufB, stats, 4, nk_w, nk_b);
  prep_cast<false, false><<<1024, 256, 0, stream>>>(Y, bufC, stats, 0, nq_w, nq_b);
  cast_w<<<160, 256, 0, stream>>>(Wq, Wk, Wv, Wo, Wres, bufW);

  // 3. projections. Q pre-scaled by log2(e)/sqrt(256) (exp2 domain);
  //    V stored transposed per batch.
  const float qscale = 1.4426950408889634f / 16.f;
  gemm_nt<GM_F16><<<dim3(128, 4), 256, 0, stream>>>(bufA, bufW + 0 * 65536, bq, nullptr, bufQ, qscale);
  gemm_nt<GM_F16><<<dim3(128, 4), 256, 0, stream>>>(bufB, bufW + 1 * 65536, bk, nullptr, bufK, 1.f);
  gemm_nt<GM_VT ><<<dim3(128, 4), 256, 0, stream>>>(bufC, bufW + 2 * 65536, bv, nullptr, bufA, 1.f);

  // 4. attention (out -> bufB), 1D grid with XCD-aware decode inside
  attn_kernel<<<1024, 256, 0, stream>>>(bufQ, bufK, bufA, bufB);

  // 5. O projection + X residual -> H1 (in d_out, f32)
  gemm_nt<GM_F32R><<<dim3(128, 4), 256, 0, stream>>>(bufB, bufW + 3 * 65536, bo, X, out, 1.f);

  // 6. stats over H1, relu(setnorm(H1)) -> bufC
  stats_partial<<<dim3(64, 4), 256, 0, stream>>>(out, out, partial);
  stats_final<<<4, 64, 0, stream>>>(partial, stats);
  prep_cast<true, true><<<1024, 256, 0, stream>>>(out, bufC, stats, 0, n0_w, n0_b);

  // 7. final: out = H1 + relu(setnorm(H1)) @ Wres^T + bres (in-place per element)
  gemm_nt<GM_F32R><<<dim3(128, 4), 256, 0, stream>>>(bufC, bufW + 4 * 65536, bres, out, out, 1.f);
}

// Round 8
// 104.274 us; speedup vs baseline: 1.8715x; 1.1538x over previous
//
#include <hip/hip_runtime.h>

// ---------------------------------------------------------------------------
// MABClean: setnorm -> {Q,K,V} proj -> 8-head attention -> O proj + residual
//           -> setnorm -> relu -> Wres proj + residual.
// B=4, Nx=Ny=2048, d_model=256, heads=8, head_dim=32. All f32 in/out.
// r8: GEMM BK=64 + coalesced swizzled staging + double-buffer; QKV fused into
// one launch; stats finalize fused into preps; Y read once. 9 launches.
// ---------------------------------------------------------------------------

typedef _Float16 f16;
typedef _Float16 f16x4 __attribute__((ext_vector_type(4)));
typedef _Float16 f16x8 __attribute__((ext_vector_type(8)));
typedef float f32x4 __attribute__((ext_vector_type(4)));
typedef unsigned int u32;
typedef unsigned int u32x2 __attribute__((ext_vector_type(2)));

#define DEV static __device__ __forceinline__

DEV void load_lds16(const void* g, void* s) {
  __builtin_amdgcn_global_load_lds(
      (const __attribute__((address_space(1))) void*)g,
      (__attribute__((address_space(3))) void*)s, 16, 0, 0);
}

DEV float fexp2(float x) {
  float r;
  asm("v_exp_f32 %0, %1" : "=v"(r) : "v"(x));
  return r;
}

DEV u32 pkh(float a, float b) {
  auto h = __builtin_amdgcn_cvt_pkrtz(a, b);  // __fp16 ext_vector(2)
  return __builtin_bit_cast(u32, h);
}

// ---------------- set-norm statistics --------------------------------------
// slice s: s<4 -> p0 batch s ; s>=4 -> p1 batch s-4. 524288 elems per slice.
__global__ __launch_bounds__(256) void stats_partial(const float* __restrict__ p0,
                                                     const float* __restrict__ p1,
                                                     float2* __restrict__ partial) {
  const int s = blockIdx.y;
  const float* p = (s >= 4 ? p1 + (size_t)(s - 4) * 524288 : p0 + (size_t)s * 524288)
                   + (size_t)blockIdx.x * 8192;
  float sum = 0.f, ss = 0.f;
#pragma unroll
  for (int j = 0; j < 8; ++j) {
    f32x4 v = *reinterpret_cast<const f32x4*>(p + (size_t)(j * 256 + threadIdx.x) * 4);
#pragma unroll
    for (int e = 0; e < 4; ++e) { sum += v[e]; ss += v[e] * v[e]; }
  }
#pragma unroll
  for (int m = 1; m < 64; m <<= 1) { sum += __shfl_xor(sum, m); ss += __shfl_xor(ss, m); }
  __shared__ float2 red[4];
  if ((threadIdx.x & 63) == 0) red[threadIdx.x >> 6] = make_float2(sum, ss);
  __syncthreads();
  if (threadIdx.x == 0) {
    float a = 0.f, b = 0.f;
    for (int i = 0; i < 4; ++i) { a += red[i].x; b += red[i].y; }
    partial[s * 64 + blockIdx.x] = make_float2(a, b);
  }
}

// per-wave finalize: reduce 64 partials of slice s (all lanes get the result)
DEV float2 finalize_stats(const float2* __restrict__ partial, int s) {
  const int lane = threadIdx.x & 63;
  float2 v = partial[s * 64 + lane];
  float sum = v.x, ss = v.y;
#pragma unroll
  for (int m = 1; m < 64; m <<= 1) { sum += __shfl_xor(sum, m); ss += __shfl_xor(ss, m); }
  const float invN = 1.f / 524288.f;
  const float mean = sum * invN;
  const float var = fmaxf(ss * invN - mean * mean, 0.f);
  return make_float2(mean, rsqrtf(var + 1e-5f));
}

// ---------------- fused preps ----------------------------------------------
// blocks 0..1023: Xn = setnorm(X)  (slices 0-3)
// blocks 1024..2047: Yn = setnorm(Y) (slices 4-7) AND Yc = cast(Y)
__global__ __launch_bounds__(256) void prep_xy(const float* __restrict__ X,
                                               const float* __restrict__ Y,
                                               f16* __restrict__ Xn, f16* __restrict__ Yn,
                                               f16* __restrict__ Yc,
                                               const float2* __restrict__ partial,
                                               const float* __restrict__ nqw, const float* __restrict__ nqb,
                                               const float* __restrict__ nkw, const float* __restrict__ nkb) {
  const int bid = blockIdx.x;
  const bool isX = bid < 1024;
  const size_t idx = ((size_t)(isX ? bid : bid - 1024) * 256 + threadIdx.x) * 8;
  const int slice = (int)(idx >> 19);
  const float2 st = finalize_stats(partial, (isX ? 0 : 4) + slice);
  const int f = (int)(idx & 255);
  const float* in = isX ? X : Y;
  f32x4 v0 = *reinterpret_cast<const f32x4*>(in + idx);
  f32x4 v1 = *reinterpret_cast<const f32x4*>(in + idx + 4);
  const float* wv = isX ? nqw : nkw;
  const float* bv = isX ? nqb : nkb;
  f32x4 w0 = *reinterpret_cast<const f32x4*>(wv + f);
  f32x4 w1 = *reinterpret_cast<const f32x4*>(wv + f + 4);
  f32x4 b0 = *reinterpret_cast<const f32x4*>(bv + f);
  f32x4 b1 = *reinterpret_cast<const f32x4*>(bv + f + 4);
  f16x8 on;
#pragma unroll
  for (int j = 0; j < 4; ++j) {
    on[j]     = (f16)((v0[j] - st.x) * st.y * w0[j] + b0[j]);
    on[j + 4] = (f16)((v1[j] - st.x) * st.y * w1[j] + b1[j]);
  }
  if (isX) {
    *reinterpret_cast<f16x8*>(Xn + idx) = on;
  } else {
    *reinterpret_cast<f16x8*>(Yn + idx) = on;
    f16x8 oc;
#pragma unroll
    for (int j = 0; j < 4; ++j) { oc[j] = (f16)v0[j]; oc[j + 4] = (f16)v1[j]; }
    *reinterpret_cast<f16x8*>(Yc + idx) = oc;
  }
}

// relu(setnorm(H)) -> f16 (slices 0-3 of partial)
__global__ __launch_bounds__(256) void prep_h(const float* __restrict__ H, f16* __restrict__ out,
                                              const float2* __restrict__ partial,
                                              const float* __restrict__ w, const float* __restrict__ b) {
  const size_t idx = ((size_t)blockIdx.x * 256 + threadIdx.x) * 8;
  const float2 st = finalize_stats(partial, (int)(idx >> 19));
  const int f = (int)(idx & 255);
  f32x4 v0 = *reinterpret_cast<const f32x4*>(H + idx);
  f32x4 v1 = *reinterpret_cast<const f32x4*>(H + idx + 4);
  f32x4 w0 = *reinterpret_cast<const f32x4*>(w + f);
  f32x4 w1 = *reinterpret_cast<const f32x4*>(w + f + 4);
  f32x4 b0 = *reinterpret_cast<const f32x4*>(b + f);
  f32x4 b1 = *reinterpret_cast<const f32x4*>(b + f + 4);
  f16x8 o;
#pragma unroll
  for (int j = 0; j < 4; ++j) {
    o[j]     = (f16)fmaxf((v0[j] - st.x) * st.y * w0[j] + b0[j], 0.f);
    o[j + 4] = (f16)fmaxf((v1[j] - st.x) * st.y * w1[j] + b1[j], 0.f);
  }
  *reinterpret_cast<f16x8*>(out + idx) = o;
}

// weights: 5 x [256x256] f32 -> concat f16. grid 160 x 256.
__global__ __launch_bounds__(256) void cast_w(const float* __restrict__ w0, const float* __restrict__ w1,
                                              const float* __restrict__ w2, const float* __restrict__ w3,
                                              const float* __restrict__ w4, f16* __restrict__ out) {
  const int i8 = blockIdx.x * 256 + threadIdx.x;  // 0..40959
  const int mat = i8 >> 13;
  const size_t off = (size_t)(i8 & 8191) * 8;
  const float* src = mat == 0 ? w0 : mat == 1 ? w1 : mat == 2 ? w2 : mat == 3 ? w3 : w4;
  f32x4 v0 = *reinterpret_cast<const f32x4*>(src + off);
  f32x4 v1 = *reinterpret_cast<const f32x4*>(src + off + 4);
  f16x8 o;
#pragma unroll
  for (int j = 0; j < 4; ++j) { o[j] = (f16)v0[j]; o[j + 4] = (f16)v1[j]; }
  *reinterpret_cast<f16x8*>(out + (size_t)mat * 65536 + off) = o;
}

// ---------------- GEMM core: C[64x64] tile = A[64xK].W[64xK]^T, K=256 ------
// BK=64, double-buffered LDS, coalesced swizzled staging (rule: swizzle both
// the global source column and the LDS read with the same involution).
// LDS layout per buffer: A: [64 rows][8 kg-slots][8], kg stored at slot
// kg^((row>>1)&3) within each half (kg 0-3 -> first 2048, 4-7 -> second).
enum { GM_F16 = 0, GM_VT = 1, GM_F32R = 2 };

struct GemmPtrs {
  const f16* A; const f16* W; const float* bias; const float* resid;
  void* out; float scale; int mode;
};

template <bool QKV>
__global__ __launch_bounds__(256) void gemm_nt(const f16* __restrict__ A0, const f16* __restrict__ A1,
                                               const f16* __restrict__ A2, const f16* __restrict__ Wc,
                                               const float* __restrict__ b0, const float* __restrict__ b1,
                                               const float* __restrict__ b2,
                                               const float* __restrict__ resid,
                                               void* o0p, void* o1p, void* o2p,
                                               float scale0, int mode0) {
  __shared__ __align__(16) f16 lds[2][8192];  // [buf][A 4096 | B 4096]
  const int t = threadIdx.x;
  const int w = t >> 6, lane = t & 63;
  const int g = lane >> 4, lq = lane & 15;
  const int m0 = blockIdx.x * 64, n0 = blockIdx.y * 64;
  const int wr = (w >> 1) * 32, wc = (w & 1) * 32;
  const int z = QKV ? blockIdx.z : 0;

  const f16* A = QKV ? (z == 0 ? A0 : z == 1 ? A1 : A2) : A0;
  const f16* W = QKV ? (Wc + z * 65536) : Wc;
  const float* bias = QKV ? (z == 0 ? b0 : z == 1 ? b1 : b2) : b0;
  void* outp = QKV ? (z == 0 ? o0p : z == 1 ? o1p : o2p) : o0p;
  const float scale = (QKV && z != 0) ? 1.f : scale0;
  const int mode = QKV ? (z == 2 ? GM_VT : GM_F16) : mode0;

  // staging: thread t -> row r=t>>2, slot c0=t&3; global kg = c0 ^ sw (both halves)
  const int r_ = t >> 2, c0 = t & 3, sw = (t >> 3) & 3;
  const int kgA = (c0 ^ sw) << 3;  // elem offset of swizzled kg (first half)
  const f16* gA = A + (size_t)(m0 + r_) * 256 + kgA;
  const f16* gB = W + (size_t)(n0 + r_) * 256 + kgA;
  f16* dA0 = &lds[0][0] + t * 8;
  f16* dA1 = &lds[1][0] + t * 8;

  f32x4 acc[2][2] = {};

  auto stage = [&](int kt, int buf) {
    f16* base = buf ? dA1 : dA0;
    const int ko = kt * 64;
    load_lds16(gA + ko, base);                 // A kg 0-3
    load_lds16(gA + ko + 32, base + 2048);     // A kg 4-7
    load_lds16(gB + ko, base + 4096);          // B kg 0-3
    load_lds16(gB + ko + 32, base + 6144);     // B kg 4-7
  };

  const int swr = ((lq >> 1) & 3);  // read-side swizzle (row>>1)&3 == (lq>>1)&3
  auto compute = [&](int buf) {
    const f16* L = &lds[buf][0];
#pragma unroll
    for (int kk = 0; kk < 2; ++kk) {
      f16x8 af[2], bf[2];
#pragma unroll
      for (int i = 0; i < 2; ++i)
        af[i] = *reinterpret_cast<const f16x8*>(L + kk * 2048 + (wr + i * 16 + lq) * 32 + ((g ^ swr) << 3));
#pragma unroll
      for (int j = 0; j < 2; ++j)
        bf[j] = *reinterpret_cast<const f16x8*>(L + 4096 + kk * 2048 + (wc + j * 16 + lq) * 32 + ((g ^ swr) << 3));
#pragma unroll
      for (int i = 0; i < 2; ++i)
#pragma unroll
        for (int j = 0; j < 2; ++j)
          acc[i][j] = __builtin_amdgcn_mfma_f32_16x16x32_f16(af[i], bf[j], acc[i][j], 0, 0, 0);
    }
  };

  stage(0, 0);
  __syncthreads();
  stage(1, 1); compute(0); __syncthreads();
  stage(2, 0); compute(1); __syncthreads();
  stage(3, 1); compute(0); __syncthreads();
  compute(1);

#pragma unroll
  for (int i = 0; i < 2; ++i)
#pragma unroll
    for (int j = 0; j < 2; ++j) {
      const int row0 = m0 + wr + i * 16 + g * 4;
      const int col = n0 + wc + j * 16 + lq;
      const float bv = bias[col];
#pragma unroll
      for (int r = 0; r < 4; ++r) {
        const int rr = row0 + r;
        float v = (acc[i][j][r] + bv) * scale;
        if (mode == GM_F16) {
          ((f16*)outp)[(size_t)rr * 256 + col] = (f16)v;
        } else if (mode == GM_VT) {
          ((f16*)outp)[((size_t)(rr >> 11) * 256 + col) * 2048 + (rr & 2047)] = (f16)v;
        } else {
          const size_t o = (size_t)rr * 256 + col;
          ((float*)outp)[o] = v + resid[o];
        }
      }
    }
}

// ---------------- flash attention (r7, unchanged) ---------------------------
__global__ __launch_bounds__(256) void attn_kernel(const f16* __restrict__ Q,
                                                   const f16* __restrict__ K,
                                                   const f16* __restrict__ Vt,
                                                   f16* __restrict__ O) {
  __shared__ __align__(16) f16 kbuf[2][2048];
  __shared__ __align__(16) f16 vbuf[2][2048];
  __shared__ __align__(16) f16 plds[4][1024];
  const int t = threadIdx.x;
  const int w = t >> 6, lane = t & 63;
  const int g = lane >> 4, lq = lane & 15;
  const int wg = blockIdx.x;
  const int linear = (wg & 7) * 128 + (wg >> 3);
  const int qt = linear & 31;
  const int hb = linear >> 5;
  const int h = hb & 7, b = hb >> 3;
  const int q0 = qt * 64 + w * 16;
  const float THR = 8.0f;

  const f16* Kb = K + (size_t)b * 2048 * 256 + h * 32;
  const f16* Vb = Vt + ((size_t)b * 256 + h * 32) * 2048;
  f16* myp = plds[w];

  const f16x8 qf =
      *reinterpret_cast<const f16x8*>(Q + (size_t)(b * 2048 + q0 + lq) * 256 + h * 32 + g * 8);

  const f16* gK = Kb + (size_t)(t >> 2) * 256 +
                  (((t & 3) ^ ((t >> 2) & 3) ^ ((t >> 4) & 3)) << 3);
  const f16* gV = Vb + (size_t)(t >> 3) * 2048 + ((((t & 7) ^ ((t >> 3) & 7))) << 3);
  f16* dKa = &kbuf[0][0] + t * 8;
  f16* dKb = &kbuf[1][0] + t * 8;
  f16* dVa = &vbuf[0][0] + t * 8;
  f16* dVb = &vbuf[1][0] + t * 8;
  const int KSTEP = 64 * 256;

  const int swk = ((g ^ (lq & 3) ^ ((lq >> 2) & 3)) << 3);
  const int kro = lq * 32 + swk;
  const int svA = ((g ^ (lq & 7)) << 3);
  const int svB = (((4 + g) ^ (lq & 7)) << 3);
  const int vr0 = lq * 64, vr1 = (16 + lq) * 64;

  const int xq = (lq & 7) << 3;
  f16* wp0 = myp + ((lq * 64 + g * 4 + 0) ^ xq);
  f16* wp1 = myp + ((lq * 64 + g * 4 + 16) ^ xq);
  f16* wp2 = myp + ((lq * 64 + g * 4 + 32) ^ xq);
  f16* wp3 = myp + ((lq * 64 + g * 4 + 48) ^ xq);
  const f16* rp0 = myp + ((lq * 64 + 0 + g * 8) ^ xq);
  const f16* rp1 = myp + ((lq * 64 + 32 + g * 8) ^ xq);

  f32x4 o0 = {0.f, 0.f, 0.f, 0.f}, o1 = {0.f, 0.f, 0.f, 0.f};
  float m_ = -1e30f;
  float l_ = 0.f;

  auto compute = [&](int buf) {
    const f16* kb = &kbuf[buf][0];
    const f16* vb = &vbuf[buf][0];
    f16x8 kf0 = *reinterpret_cast<const f16x8*>(kb + kro);
    f16x8 kf1 = *reinterpret_cast<const f16x8*>(kb + 512 + kro);
    f16x8 kf2 = *reinterpret_cast<const f16x8*>(kb + 1024 + kro);
    f16x8 kf3 = *reinterpret_cast<const f16x8*>(kb + 1536 + kro);

    const f32x4 z = {0.f, 0.f, 0.f, 0.f};
    __builtin_amdgcn_s_setprio(1);
    f32x4 s0 = __builtin_amdgcn_mfma_f32_16x16x32_f16(kf0, qf, z, 0, 0, 0);
    f32x4 s1 = __builtin_amdgcn_mfma_f32_16x16x32_f16(kf1, qf, z, 0, 0, 0);
    f32x4 s2 = __builtin_amdgcn_mfma_f32_16x16x32_f16(kf2, qf, z, 0, 0, 0);
    f32x4 s3 = __builtin_amdgcn_mfma_f32_16x16x32_f16(kf3, qf, z, 0, 0, 0);
    __builtin_amdgcn_s_setprio(0);

    float t0 = fmaxf(fmaxf(s0[0], s0[1]), s0[2]);
    float t1 = fmaxf(fmaxf(s0[3], s1[0]), s1[1]);
    float t2 = fmaxf(fmaxf(s1[2], s1[3]), s2[0]);
    float t3 = fmaxf(fmaxf(s2[1], s2[2]), s2[3]);
    float t4 = fmaxf(fmaxf(s3[0], s3[1]), s3[2]);
    float x = fmaxf(fmaxf(fmaxf(t0, t1), fmaxf(t2, t3)), fmaxf(t4, s3[3]));
    x = fmaxf(x, __shfl_xor(x, 16));
    x = fmaxf(x, __shfl_xor(x, 32));

    if (__any(x > m_ + THR)) {
      const float mnew = fmaxf(m_, x);
      const float sc = fexp2(m_ - mnew);
      m_ = mnew;
      l_ *= sc;
#pragma unroll
      for (int r = 0; r < 4; ++r) {
        const float scq = __shfl(sc, g * 4 + r);
        o0[r] *= scq;
        o1[r] *= scq;
      }
    }

    float e00 = fexp2(s0[0] - m_), e01 = fexp2(s0[1] - m_), e02 = fexp2(s0[2] - m_), e03 = fexp2(s0[3] - m_);
    float e10 = fexp2(s1[0] - m_), e11 = fexp2(s1[1] - m_), e12 = fexp2(s1[2] - m_), e13 = fexp2(s1[3] - m_);
    float e20 = fexp2(s2[0] - m_), e21 = fexp2(s2[1] - m_), e22 = fexp2(s2[2] - m_), e23 = fexp2(s2[3] - m_);
    float e30 = fexp2(s3[0] - m_), e31 = fexp2(s3[1] - m_), e32 = fexp2(s3[2] - m_), e33 = fexp2(s3[3] - m_);
    const float la = (e00 + e01) + (e02 + e03);
    const float lb = (e10 + e11) + (e12 + e13);
    const float lc = (e20 + e21) + (e22 + e23);
    const float ld = (e30 + e31) + (e32 + e33);
    l_ += (la + lb) + (lc + ld);

    u32x2 w0q = {pkh(e00, e01), pkh(e02, e03)};
    u32x2 w1q = {pkh(e10, e11), pkh(e12, e13)};
    u32x2 w2q = {pkh(e20, e21), pkh(e22, e23)};
    u32x2 w3q = {pkh(e30, e31), pkh(e32, e33)};
    *reinterpret_cast<u32x2*>(wp0) = w0q;
    *reinterpret_cast<u32x2*>(wp1) = w1q;
    *reinterpret_cast<u32x2*>(wp2) = w2q;
    *reinterpret_cast<u32x2*>(wp3) = w3q;

    f16x8 pa0 = *reinterpret_cast<const f16x8*>(rp0);
    f16x8 pa1 = *reinterpret_cast<const f16x8*>(rp1);
    f16x8 v00 = *reinterpret_cast<const f16x8*>(vb + vr0 + svA);
    f16x8 v01 = *reinterpret_cast<const f16x8*>(vb + vr0 + svB);
    f16x8 v10 = *reinterpret_cast<const f16x8*>(vb + vr1 + svA);
    f16x8 v11 = *reinterpret_cast<const f16x8*>(vb + vr1 + svB);
    __builtin_amdgcn_s_setprio(1);
    o0 = __builtin_amdgcn_mfma_f32_16x16x32_f16(pa0, v00, o0, 0, 0, 0);
    o1 = __builtin_amdgcn_mfma_f32_16x16x32_f16(pa0, v10, o1, 0, 0, 0);
    o0 = __builtin_amdgcn_mfma_f32_16x16x32_f16(pa1, v01, o0, 0, 0, 0);
    o1 = __builtin_amdgcn_mfma_f32_16x16x32_f16(pa1, v11, o1, 0, 0, 0);
    __builtin_amdgcn_s_setprio(0);
  };

  load_lds16(gK, dKa);
  load_lds16(gV, dVa);
  gK += KSTEP; gV += 64;
  __syncthreads();

  for (int kt = 0; kt < 32; kt += 2) {
    load_lds16(gK, dKb);
    load_lds16(gV, dVb);
    gK += KSTEP; gV += 64;
    compute(0);
    __syncthreads();
    if (kt < 30) {
      load_lds16(gK, dKa);
      load_lds16(gV, dVa);
      gK += KSTEP; gV += 64;
    }
    compute(1);
    __syncthreads();
  }

  float lf = l_ + __shfl_xor(l_, 16);
  lf += __shfl_xor(lf, 32);
#pragma unroll
  for (int r = 0; r < 4; ++r) {
    const float lr = __shfl(lf, g * 4 + r);
    const float inv = 1.f / lr;
    const size_t row = (size_t)b * 2048 + q0 + g * 4 + r;
    O[row * 256 + h * 32 + lq] = (f16)(o0[r] * inv);
    O[row * 256 + h * 32 + 16 + lq] = (f16)(o1[r] * inv);
  }
}

// ---------------------------------------------------------------------------
extern "C" void kernel_launch(void* const* d_in, const int* in_sizes, int n_in,
                              void* d_out, int out_size, void* d_ws, size_t ws_size,
                              hipStream_t stream) {
  (void)in_sizes; (void)n_in; (void)out_size; (void)ws_size;
  const float* X    = (const float*)d_in[0];
  const float* Y    = (const float*)d_in[1];
  const float* Wq   = (const float*)d_in[2];
  const float* bq   = (const float*)d_in[3];
  const float* Wk   = (const float*)d_in[4];
  const float* bk   = (const float*)d_in[5];
  const float* Wv   = (const float*)d_in[6];
  const float* bv   = (const float*)d_in[7];
  const float* Wo   = (const float*)d_in[8];
  const float* bo   = (const float*)d_in[9];
  const float* Wres = (const float*)d_in[10];
  const float* bres = (const float*)d_in[11];
  const float* nq_w = (const float*)d_in[12];
  const float* nq_b = (const float*)d_in[13];
  const float* nk_w = (const float*)d_in[14];
  const float* nk_b = (const float*)d_in[15];
  const float* n0_w = (const float*)d_in[16];
  const float* n0_b = (const float*)d_in[17];
  float* out = (float*)d_out;

  // workspace (~25 MB): six 4MiB f16 buffers + 640KiB weights + partials
  char* ws = (char*)d_ws;
  const size_t MB = 1u << 20;
  f16* bufXn = (f16*)(ws + 0 * MB);    // Xn -> attn out
  f16* bufYn = (f16*)(ws + 4 * MB);
  f16* bufYc = (f16*)(ws + 8 * MB);    // Ycast -> reluH
  f16* bufQ  = (f16*)(ws + 12 * MB);
  f16* bufK  = (f16*)(ws + 16 * MB);
  f16* bufVt = (f16*)(ws + 20 * MB);
  f16* bufW  = (f16*)(ws + 24 * MB);   // 5 x 65536 f16
  float2* partial = (float2*)(ws + 24 * MB + 700 * 1024);

  // 1. stats for X (slices 0-3) and Y (slices 4-7)
  stats_partial<<<dim3(64, 8), 256, 0, stream>>>(X, Y, partial);

  // 2. weight cast + fused preps (finalize stats per-wave in-kernel)
  cast_w<<<160, 256, 0, stream>>>(Wq, Wk, Wv, Wo, Wres, bufW);
  prep_xy<<<2048, 256, 0, stream>>>(X, Y, bufXn, bufYn, bufYc, partial,
                                    nq_w, nq_b, nk_w, nk_b);

  // 3. Q/K/V projections fused (grid.z). Q pre-scaled by log2(e)/sqrt(256);
  //    V stored transposed per batch.
  const float qscale = 1.4426950408889634f / 16.f;
  gemm_nt<true><<<dim3(128, 4, 3), 256, 0, stream>>>(
      bufXn, bufYn, bufYc, bufW, bq, bk, bv, nullptr,
      bufQ, bufK, bufVt, qscale, GM_F16);

  // 4. attention (out -> bufXn)
  attn_kernel<<<1024, 256, 0, stream>>>(bufQ, bufK, bufVt, bufXn);

  // 5. O projection + X residual -> H1 (d_out, f32)
  gemm_nt<false><<<dim3(128, 4), 256, 0, stream>>>(
      bufXn, nullptr, nullptr, bufW + 3 * 65536, bo, nullptr, nullptr, X,
      out, nullptr, nullptr, 1.f, GM_F32R);

  // 6. stats over H1; relu(setnorm(H1)) -> bufYc
  stats_partial<<<dim3(64, 4), 256, 0, stream>>>(out, out, partial);
  prep_h<<<1024, 256, 0, stream>>>(out, bufYc, partial, n0_w, n0_b);

  // 7. final: out = H1 + relu(setnorm(H1)) @ Wres^T + bres
  gemm_nt<false><<<dim3(128, 4), 256, 0, stream>>>(
      bufYc, nullptr, nullptr, bufW + 4 * 65536, bres, nullptr, nullptr, out,
      out, nullptr, nullptr, 1.f, GM_F32R);
}